// Round 6
// baseline (343.606 us; speedup 1.0000x reference)
//
#include <hip/hip_runtime.h>
#include <math.h>

static constexpr int B_ = 8, C_ = 512, T_ = 2048, C3_ = 1536;
static constexpr float INV_TEMP = 1.0f / 0.07f;

typedef __attribute__((ext_vector_type(8))) short short8;
typedef __attribute__((ext_vector_type(4))) float floatx4;

__device__ __forceinline__ float b2f(unsigned short u) {
  union { unsigned int i; float f; } v; v.i = ((unsigned int)u) << 16; return v.f;
}
__device__ __forceinline__ unsigned short f2b(float f) {
  union { float f; unsigned int i; } v; v.f = f;
  const unsigned int x = v.i;
  return (unsigned short)((x + 0x7FFFu + ((x >> 16) & 1u)) >> 16);
}
__device__ __forceinline__ void gld16(const unsigned short* g, unsigned short* l) {
  __builtin_amdgcn_global_load_lds(
      (const __attribute__((address_space(1))) void*)g,
      (__attribute__((address_space(3))) void*)l, 16, 0, 0);
}

// ---------------------------------------------------------------------------
// TN-form bf16 MFMA GEMM: C[m,n] = sum_k A[m,k]*B[n,k], A:[M,K] B:[N,K],
// both k-contiguous bf16. TM x 128 tile (TM=128: 2x2 waves of 64x64, 32KB
// LDS -> 5 blocks/CU; TM=64: 2x2 waves of 32x64, 24KB -> 6 blocks/CU).
// BK=32, 16x16x32 MFMA, 2-deep LDS ring. K-loop body ordering is
// barrier -> ds_read fragments -> prefetch gld16 -> MFMA, so the compiler's
// conservative vmcnt-before-ds_read only waits on the already-drained tile,
// never on the fresh prefetch. Latency hiding comes from 4-6 blocks/CU TLP.
// MODE 0: plain store.
// MODE 2: softmax epilogue — s = acc*rs[row]*cs[col]*scale; p = exp(s-scale)
//         (scale = 1/TEMP bounds the score, so no row-max pass needed);
//         store bf16 p; atomically add row sums of ROUNDED p into denom.
// MODE 3: row divide — v = acc / rs[row]  (softmax denominator, in AV).
// ---------------------------------------------------------------------------
template<int TM, bool OUT_BF16, int MODE>
__global__ __launch_bounds__(256)
void gemm_tn(const unsigned short* __restrict__ A, const unsigned short* __restrict__ B,
             void* __restrict__ Cout, int K, int lda, int ldb, int ldc,
             long long sA, long long sB, long long sC,
             const float* __restrict__ rs, const float* __restrict__ cs,
             float* __restrict__ denom, int rcStride, float scale)
{
  constexpr int NFA = TM / 64 * 2;         // A fragments per wave (4 or 2)

  const int bz = blockIdx.z;
  A += (long long)bz * sA;
  B += (long long)bz * sB;
  if (MODE == 2) { rs += (long long)bz * rcStride; cs += (long long)bz * rcStride;
                   denom += (long long)bz * rcStride; }
  if (MODE == 3) { rs += (long long)bz * rcStride; }
  const int m0 = blockIdx.y * TM, n0 = blockIdx.x * 128;
  const int tid = threadIdx.x;
  const int w = tid >> 6, lane = tid & 63;
  const int wm = (w >> 1) * (TM / 2), wn = (w & 1) * 64;
  const int rl = lane & 15, qd = lane >> 4;

  __shared__ __align__(16) unsigned short As[2][TM * 32];
  __shared__ __align__(16) unsigned short Bs[2][128 * 32];

  // staging: lane -> (row sr, granule slot sg); global granule XOR-swizzled
  const int sr = lane >> 2, sg = lane & 3;
  // A rows covered per wave: TM=128 -> rows 32w+sr, +16 (2 gld); TM=64 -> 16w+sr (1 gld)
  const int aml0 = (TM == 128 ? 32 * w : 16 * w) + sr, aml1 = aml0 + 16;
  const int aq0 = sg ^ ((aml0 >> 1) & 3), aq1 = sg ^ ((aml1 >> 1) & 3);
  const unsigned short* gA0 = A + (long long)(m0 + aml0) * lda + aq0 * 8;
  const unsigned short* gA1 = A + (long long)(m0 + aml1) * lda + aq1 * 8;
  const int bml0 = 32 * w + sr, bml1 = bml0 + 16;
  const int bq0 = sg ^ ((bml0 >> 1) & 3), bq1 = sg ^ ((bml1 >> 1) & 3);
  const unsigned short* gB0 = B + (long long)(n0 + bml0) * ldb + bq0 * 8;
  const unsigned short* gB1 = B + (long long)(n0 + bml1) * ldb + bq1 * 8;

  // fragment read offsets (swizzle-corrected)
  int aoff[NFA], boff[4];
  #pragma unroll
  for (int i = 0; i < NFA; ++i) {
    const int mr = wm + i * 16 + rl;
    aoff[i] = mr * 32 + ((qd ^ ((mr >> 1) & 3)) * 8);
  }
  #pragma unroll
  for (int j = 0; j < 4; ++j) {
    const int nr = wn + j * 16 + rl;
    boff[j] = nr * 32 + ((qd ^ ((nr >> 1) & 3)) * 8);
  }

  floatx4 acc[NFA][4];
  #pragma unroll
  for (int i = 0; i < NFA; ++i)
    #pragma unroll
    for (int j = 0; j < 4; ++j) acc[i][j] = 0.0f;

  auto stage = [&](int t, int bf) {
    const int ko = t * 32;
    gld16(gA0 + ko, As[bf] + (TM == 128 ? 32 * w : 16 * w) * 32);
    if (TM == 128) gld16(gA1 + ko, As[bf] + (32 * w + 16) * 32);
    gld16(gB0 + ko, Bs[bf] + (32 * w) * 32);
    gld16(gB1 + ko, Bs[bf] + (32 * w + 16) * 32);
  };

  const int niter = K >> 5;
  stage(0, 0);
  for (int i = 0; i < niter; ++i) {
    const int buf = i & 1;
    __syncthreads();   // drains stage(i); WAR-protects buf^1 (read in i-1)
    // 1) fragment reads first — only depend on the drained tile
    short8 fa[NFA], fb[4];
    #pragma unroll
    for (int ii = 0; ii < NFA; ++ii) fa[ii] = *(const short8*)(As[buf] + aoff[ii]);
    #pragma unroll
    for (int j = 0; j < 4; ++j) fb[j] = *(const short8*)(Bs[buf] + boff[j]);
    // 2) then issue the next tile's loads (stay in flight through the MFMAs)
    if (i + 1 < niter) stage(i + 1, buf ^ 1);
    // 3) MFMA
    #pragma unroll
    for (int ii = 0; ii < NFA; ++ii)
      #pragma unroll
      for (int j = 0; j < 4; ++j)
        acc[ii][j] = __builtin_amdgcn_mfma_f32_16x16x32_bf16(fa[ii], fb[j], acc[ii][j], 0, 0, 0);
  }

  // epilogue: C/D layout col=lane&15, row=(lane>>4)*4+reg
  #pragma unroll
  for (int i = 0; i < NFA; ++i) {
    #pragma unroll
    for (int r = 0; r < 4; ++r) {
      const int row = m0 + wm + i * 16 + qd * 4 + r;
      float rowf = 0.f;
      if (MODE == 2) rowf = rs[row] * scale;
      if (MODE == 3) rowf = 1.0f / rs[row];
      float rsum = 0.f;
      #pragma unroll
      for (int j = 0; j < 4; ++j) {
        const int col = n0 + wn + j * 16 + rl;
        float v = acc[i][j][r];
        if (MODE == 2) {
          const float s = v * rowf * cs[col];
          const unsigned short pb = f2b(__expf(s - scale));
          rsum += b2f(pb);   // sum the ROUNDED weights
          ((unsigned short*)Cout)[(long long)bz * sC + (long long)row * ldc + col] = pb;
          continue;
        }
        if (MODE == 3) v *= rowf;
        const long long idx = (long long)bz * sC + (long long)row * ldc + col;
        if (OUT_BF16) ((unsigned short*)Cout)[idx] = f2b(v);
        else          ((float*)Cout)[idx] = v;
      }
      if (MODE == 2) {
        // reduce over the 16 rl lanes (xor masks < 16 stay within qd group)
        #pragma unroll
        for (int m = 1; m < 16; m <<= 1) rsum += __shfl_xor(rsum, m);
        if (rl == 0) atomicAdd(denom + row, rsum);
      }
    }
  }
}

__global__ __launch_bounds__(256)
void zero_f(float* __restrict__ p, int n)
{
  const int i = blockIdx.x * 256 + threadIdx.x;
  if (i < n) p[i] = 0.f;
}

// ---------------------------------------------------------------------------
// x [B,C,T] fp32 -> xT [B,T,C] bf16 (transpose-convert, 32x32 LDS tiles)
// ---------------------------------------------------------------------------
__global__ __launch_bounds__(256)
void conv_xT(const float* __restrict__ x, unsigned short* __restrict__ xT)
{
  const int b = blockIdx.z, t0 = blockIdx.x * 32, c0 = blockIdx.y * 32;
  const int tx = threadIdx.x & 31, ty = threadIdx.x >> 5;
  __shared__ float tile[32][33];
  const float* src = x + (long long)b * C_ * T_;
  #pragma unroll
  for (int r = 0; r < 4; ++r)
    tile[ty + 8 * r][tx] = src[(long long)(c0 + ty + 8 * r) * T_ + t0 + tx];
  __syncthreads();
  unsigned short* dst = xT + (long long)b * T_ * C_;
  #pragma unroll
  for (int r = 0; r < 4; ++r)
    dst[(long long)(t0 + ty + 8 * r) * C_ + c0 + tx] = f2b(tile[tx][ty + 8 * r]);
}

__global__ __launch_bounds__(256)
void conv_bf(const float* __restrict__ in, unsigned short* __restrict__ out, int n)
{
  const int i = blockIdx.x * 256 + threadIdx.x;
  if (i < n) out[i] = f2b(in[i]);
}

// ---------------------------------------------------------------------------
// Depthwise-3 (zero pad) on v channels [2C,3C): bf16 in [B,3C,T] -> v [B,C,T]
// ---------------------------------------------------------------------------
__global__ __launch_bounds__(256)
void dw_v(const unsigned short* __restrict__ qkv, const float* __restrict__ wdw,
          unsigned short* __restrict__ vout)
{
  const long long idx = (long long)blockIdx.x * 256 + threadIdx.x;  // [B*C*T)
  const int t = (int)(idx % T_);
  const long long rem = idx / T_;
  const int c = (int)(rem % C_), b = (int)(rem / C_);
  const unsigned short* src = qkv + ((long long)(b * C3_ + 2 * C_ + c)) * T_;
  const float* wp = wdw + (2 * C_ + c) * 3;
  const float xm = (t > 0)      ? b2f(src[t - 1]) : 0.f;
  const float x0 = b2f(src[t]);
  const float xp = (t < T_ - 1) ? b2f(src[t + 1]) : 0.f;
  vout[(long long)(b * C_ + c) * T_ + t] = f2b(fmaf(wp[0], xm, fmaf(wp[1], x0, wp[2] * xp)));
}

// ---------------------------------------------------------------------------
// Depthwise-3 + transpose for q (p=0) / k (p=1): [B,3C,T] -> [B,T,C] bf16
// ---------------------------------------------------------------------------
__global__ __launch_bounds__(256)
void dw_qk_t(const unsigned short* __restrict__ qkv, const float* __restrict__ wdw,
             unsigned short* __restrict__ qT, unsigned short* __restrict__ kT)
{
  const int bz = blockIdx.z, b = bz >> 1, p = bz & 1;
  const int t0 = blockIdx.x * 32, c0 = blockIdx.y * 32;
  const int tx = threadIdx.x & 31, ty = threadIdx.x >> 5;
  __shared__ float tin[32][34];   // [c][t-1 .. t+32]
  __shared__ float tout[32][33];  // [t][c]
  const int chb = b * C3_ + p * C_;
  #pragma unroll
  for (int r = 0; r < 4; ++r) {
    const int cy = ty + 8 * r;
    const unsigned short* src = qkv + (long long)(chb + c0 + cy) * T_;
    int t = t0 - 1 + tx;
    tin[cy][tx] = (t >= 0 && t < T_) ? b2f(src[t]) : 0.f;
    if (tx < 2) {
      const int t2 = t0 + 31 + tx;
      tin[cy][32 + tx] = (t2 < T_) ? b2f(src[t2]) : 0.f;
    }
  }
  __syncthreads();
  #pragma unroll
  for (int r = 0; r < 4; ++r) {
    const int cy = ty + 8 * r;
    const float* wp = wdw + (long long)(p * C_ + c0 + cy) * 3;
    tout[tx][cy] = fmaf(wp[0], tin[cy][tx], fmaf(wp[1], tin[cy][tx + 1], wp[2] * tin[cy][tx + 2]));
  }
  __syncthreads();
  unsigned short* dst = (p == 0 ? qT : kT) + (long long)b * T_ * C_;
  #pragma unroll
  for (int r = 0; r < 4; ++r)
    dst[(long long)(t0 + ty + 8 * r) * C_ + c0 + tx] = f2b(tout[ty + 8 * r][tx]);
}

// ---------------------------------------------------------------------------
// Row L2-norm stats from bf16 [B*T, C] rows: inv = 1/max(||row||,eps)
// ---------------------------------------------------------------------------
__global__ __launch_bounds__(256)
void norms_k(const unsigned short* __restrict__ qT, const unsigned short* __restrict__ kT,
             float* __restrict__ inv_nq, float* __restrict__ inv_nk)
{
  const int wave = threadIdx.x >> 6, lane = threadIdx.x & 63;
  const long long row = (long long)blockIdx.x * 4 + wave;
  const unsigned short* src = (blockIdx.y == 0 ? qT : kT) + row * C_ + lane * 8;
  const uint4 u = *(const uint4*)src;
  float ss = 0.f;
  const unsigned int uu[4] = {u.x, u.y, u.z, u.w};
  #pragma unroll
  for (int i = 0; i < 4; ++i) {
    const float lo = b2f(uu[i] & 0xFFFF), hi = b2f(uu[i] >> 16);
    ss = fmaf(lo, lo, ss); ss = fmaf(hi, hi, ss);
  }
  #pragma unroll
  for (int m = 32; m; m >>= 1) ss += __shfl_xor(ss, m);
  if (lane == 0)
    (blockIdx.y == 0 ? inv_nq : inv_nk)[row] = 1.f / fmaxf(sqrtf(ss), 1e-12f);
}

// ---------------------------------------------------------------------------
// Workspace arena (bytes), ~185.3 MB (layout unchanged from R5):
//  [0, 64M)    early: xT (16M) + wqkv_bf; late: av_t [B,T,C] bf16 (16M)
//  [64M,80M) qT  [80M,96M) kT  [96M,112M) vb
//  [112M,176M) attn bf16 [B,T,T] — early alias: qkv_bf (48M, dead after dw)
//  [176M,...)  wproj_bf, inv_nq, inv_nk, denom
// ---------------------------------------------------------------------------
extern "C" void kernel_launch(void* const* d_in, const int* in_sizes, int n_in,
                              void* d_out, int out_size, void* d_ws, size_t ws_size,
                              hipStream_t stream)
{
  const float* x      = (const float*)d_in[0];
  const float* w_qkv  = (const float*)d_in[1];
  const float* w_dw   = (const float*)d_in[2];
  const float* w_proj = (const float*)d_in[3];
  float* out = (float*)d_out;

  char* base = (char*)d_ws;
  unsigned short* xT      = (unsigned short*)base;                    // early
  unsigned short* wqkv_bf = (unsigned short*)(base + 16777216);       // early
  unsigned short* av_t    = (unsigned short*)base;                    // late
  char* p = base + 67108864;
  unsigned short* qT = (unsigned short*)p; p += 16777216;
  unsigned short* kT = (unsigned short*)p; p += 16777216;
  unsigned short* vb = (unsigned short*)p; p += 16777216;
  unsigned short* attn   = (unsigned short*)p;
  unsigned short* qkv_bf = (unsigned short*)p;                        // early alias
  p += 67108864;
  unsigned short* wproj_bf = (unsigned short*)p; p += 524288;
  float* inv_nq = (float*)p; p += 65536;
  float* inv_nk = (float*)p; p += 65536;
  float* denom  = (float*)p;

  const long long TC = (long long)T_ * C_, TT = (long long)T_ * T_;

  // 0) conversions + denom zero
  conv_xT<<<dim3(T_ / 32, C_ / 32, B_), 256, 0, stream>>>(x, xT);
  conv_bf<<<(C3_ * C_) / 256, 256, 0, stream>>>(w_qkv, wqkv_bf, C3_ * C_);
  conv_bf<<<(C_ * C_) / 256, 256, 0, stream>>>(w_proj, wproj_bf, C_ * C_);
  zero_f<<<(B_ * T_) / 256, 256, 0, stream>>>(denom, B_ * T_);

  // 1) qkv[b][o][t] = sum_c wqkv[o][c] * x[c][t]   (1536 blocks, 32KB LDS)
  gemm_tn<128, true, 0><<<dim3(16, 12, B_), 256, 0, stream>>>(
      wqkv_bf, xT, qkv_bf, C_, C_, C_, T_,
      0LL, TC, (long long)C3_ * T_, nullptr, nullptr, nullptr, 0, 1.f);

  // 2) depthwise conv
  dw_v<<<(int)(((long long)B_ * C_ * T_) / 256), 256, 0, stream>>>(qkv_bf, w_dw, vb);
  dw_qk_t<<<dim3(T_ / 32, C_ / 32, B_ * 2), 256, 0, stream>>>(qkv_bf, w_dw, qT, kT);

  // 3) channel-L2 stats (from bf16 values)
  norms_k<<<dim3((B_ * T_) / 4, 2), 256, 0, stream>>>(qT, kT, inv_nq, inv_nk);

  // 4) scores + fused softmax (fixed-max exp) -> attn bf16 + denom atomics
  gemm_tn<128, true, 2><<<dim3(16, 16, B_), 256, 0, stream>>>(
      qT, kT, attn, C_, C_, C_, T_,
      TC, TC, TT, inv_nq, inv_nk, denom, T_, INV_TEMP);

  // 5) av_t[b][t][c] = (sum_s attn[t][s] * v[c][s]) / denom[t]
  //    TM=64 splits t: grid 1024 blocks, v re-reads stay L2-resident
  gemm_tn<64, true, 3><<<dim3(4, 32, B_), 256, 0, stream>>>(
      attn, vb, av_t, T_, T_, T_, C_,
      TT, (long long)C_ * T_, TC, denom, nullptr, nullptr, T_, 1.f);

  // 6) out[b][o][t] = sum_c wproj[o][c] * av_t[t][c]  (TM=64: 1024 blocks)
  gemm_tn<64, false, 0><<<dim3(16, 8, B_), 256, 0, stream>>>(
      wproj_bf, av_t, out, C_, C_, C_, T_,
      0LL, TC, (long long)C_ * T_, nullptr, nullptr, nullptr, 0, 1.f);
}